// Round 6
// baseline (375.147 us; speedup 1.0000x reference)
//
#include <hip/hip_runtime.h>

// ---------------------------------------------------------------------------
// GraphVAELoss, R6. Change vs R5: arecon only — global_load_lds DMA staging.
// R3/R5 evidence: compiler sinks register-resident loads to uses regardless
// of sched_barrier (VGPR 24/36), leaving 1-2 loads in flight -> 2.7 TB/s
// latency-bound. Fix: async global->LDS DMA (cannot be sunk, no VGPR
// results), 2-phase double-buffered pipeline, 4 DMA issues in flight per
// wave during every compute phase. kli / finalize unchanged (attribution).
// ws layout (doubles): [0,2048) arecon partials, [2048,3072) kli partials.
// ---------------------------------------------------------------------------

static constexpr int BB  = 32;
static constexpr int NN  = 1024;
static constexpr int ZIc = 64;
static constexpr int ZAc = 128;
static constexpr int AB2 = 2048;                  // arecon blocks
static constexpr int KB  = 1024;                  // kli blocks

#define EPSV 1e-10f
#define SPW  0.7f

// A_true is exactly {0,1}: t==1 -> log(a); t==0 -> 0.7*log(1-a).
// Bit-identical to t*log(a)+(1-t)*log(1-a) + sparsity scale on t==0.
__device__ __forceinline__ float ll_elem(float a, float t) {
    a = (a == 0.0f) ? EPSV : ((a == 1.0f) ? (1.0f - EPSV) : a);
    float x = (t == 0.0f) ? (1.0f - a) : a;
    float s = (t == 0.0f) ? SPW : 1.0f;
    return s * __logf(x);
}

__device__ __forceinline__ float ll4(float4 a, float4 t) {
    return ll_elem(a.x, t.x) + ll_elem(a.y, t.y) +
           ll_elem(a.z, t.z) + ll_elem(a.w, t.w);
}

// async global->LDS DMA, 16B per lane; LDS dest = wave-uniform base + lane*16
// (per-lane dest pointers are consistent with that mapping here: linear).
__device__ __forceinline__ void stage16(const float4* g, float4* l) {
    __builtin_amdgcn_global_load_lds(
        (const __attribute__((address_space(1))) void*)g,
        (__attribute__((address_space(3))) void*)l, 16, 0, 0);
}

__global__ __launch_bounds__(256) void arecon_kernel(
        const float4* __restrict__ Ah, const float4* __restrict__ At,
        double* __restrict__ slots) {
    // 2048 blocks; block owns 4096 float4 per array (64KB A + 64KB T),
    // processed in 8 rounds of 512 float4 (8KB) per array, double-buffered.
    __shared__ float4 bufA[2][512];
    __shared__ float4 bufT[2][512];
    const int tid  = threadIdx.x;
    const int lane = tid & 63;
    const int w    = tid >> 6;
    const size_t base4 = (size_t)blockIdx.x * 4096;

    const int o0 = w * 128 + lane;   // this lane's float4 slot, issue 0
    const int o1 = o0 + 64;          // issue 1

#define STAGE(R, PB)                                                          \
    {                                                                         \
        const float4* gA = Ah + base4 + (size_t)(R) * 512;                    \
        const float4* gT = At + base4 + (size_t)(R) * 512;                    \
        stage16(gA + o0, &bufA[PB][o0]);                                      \
        stage16(gA + o1, &bufA[PB][o1]);                                      \
        stage16(gT + o0, &bufT[PB][o0]);                                      \
        stage16(gT + o1, &bufT[PB][o1]);                                      \
    }

    STAGE(0, 0)
    __syncthreads();                 // drain round-0 DMA

    float lsum = 0.0f;
#pragma unroll 1
    for (int r = 0; r < 8; ++r) {
        const int cur = r & 1;
        if (r + 1 < 8) STAGE(r + 1, cur ^ 1)   // issue next-round DMA first
        // consume current chunk from LDS (2 float4-pairs per thread)
        float4 a0 = bufA[cur][tid];
        float4 t0 = bufT[cur][tid];
        float4 a1 = bufA[cur][256 + tid];
        float4 t1 = bufT[cur][256 + tid];
        lsum += ll4(a0, t0);
        lsum += ll4(a1, t1);
        __syncthreads();             // next buf arrived; cur safe to overwrite
    }
#undef STAGE

#pragma unroll
    for (int m = 1; m < 64; m <<= 1) lsum += __shfl_xor(lsum, m, 64);
    __shared__ float wsum[4];
    if (lane == 0) wsum[w] = lsum;
    __syncthreads();
    if (tid == 0)
        slots[blockIdx.x] = (double)(wsum[0] + wsum[1] + wsum[2] + wsum[3]);
}

// One block per node n; wave w owns b in [8w, 8w+8); lane f owns feature row f.
// z_a addresses are scalar (readfirstlane-forced wave id) -> scalar-cache
// loads. B rows double-buffered in NAMED register sets (no runtime-indexed
// arrays -> no scratch).
__global__ __launch_bounds__(256) void kli_kernel(
        const float* __restrict__ mu_i, const float* __restrict__ lv_i,
        const float* __restrict__ z_a,
        const float* __restrict__ Bmu, const float* __restrict__ Blv,
        double* __restrict__ slots) {
    const int n    = blockIdx.x;
    const int wave = __builtin_amdgcn_readfirstlane(threadIdx.x >> 6);
    const int f    = threadIdx.x & 63;

    const float4* bmu = reinterpret_cast<const float4*>(Bmu + ((size_t)n * ZIc + f) * ZAc);
    const float4* blv = reinterpret_cast<const float4*>(Blv + ((size_t)n * ZIc + f) * ZAc);

    float pm[8], pl[8];
#pragma unroll
    for (int i = 0; i < 8; ++i) { pm[i] = 0.0f; pl[i] = 0.0f; }

    float4 mA[4], lA[4], mB[4], lB[4];
#pragma unroll
    for (int q = 0; q < 4; ++q) { mA[q] = bmu[q]; lA[q] = blv[q]; }

#define KLI_COMPUTE(MV, LV, CC)                                               \
    {                                                                         \
        _Pragma("unroll")                                                     \
        for (int bi = 0; bi < 8; ++bi) {                                      \
            const int b = wave * 8 + bi;                                      \
            const float* zp = z_a + b * ZAc + (CC) * 16;                      \
            _Pragma("unroll")                                                 \
            for (int q = 0; q < 4; ++q) {                                     \
                float4 zz = *reinterpret_cast<const float4*>(zp + 4 * q);     \
                pm[bi] += MV[q].x * zz.x + MV[q].y * zz.y +                   \
                          MV[q].z * zz.z + MV[q].w * zz.w;                    \
                pl[bi] += LV[q].x * zz.x + LV[q].y * zz.y +                   \
                          LV[q].z * zz.z + LV[q].w * zz.w;                    \
            }                                                                 \
        }                                                                     \
    }

#pragma unroll 1
    for (int c = 0; c < 8; c += 2) {
#pragma unroll
        for (int q = 0; q < 4; ++q) { mB[q] = bmu[(c + 1) * 4 + q]; lB[q] = blv[(c + 1) * 4 + q]; }
        KLI_COMPUTE(mA, lA, c)
        if (c + 2 < 8) {
#pragma unroll
            for (int q = 0; q < 4; ++q) { mA[q] = bmu[(c + 2) * 4 + q]; lA[q] = blv[(c + 2) * 4 + q]; }
        }
        KLI_COMPUTE(mB, lB, c + 1)
    }
#undef KLI_COMPUTE

    double local = 0.0;
#pragma unroll
    for (int bi = 0; bi < 8; ++bi) {
        const int b = wave * 8 + bi;
        const size_t base = ((size_t)b * NN + n) * ZIc + f;
        float m1  = mu_i[base];
        float lv1 = lv_i[base];
        float d   = lv1 - pl[bi];                   // log-det ratio element
        float dm  = pm[bi] - m1;
        float sc  = __expf(d) + dm * dm * __expf(-pl[bi]);   // trace + inner
        float sd  = d;
#pragma unroll
        for (int m = 1; m < 64; m <<= 1) {
            sd += __shfl_xor(sd, m, 64);
            sc += __shfl_xor(sc, m, 64);
        }
        if (f == 0)
            local += (double)(0.5f * __expf(sd) - 64.0f + sc);
    }
    __shared__ double wacc[4];
    if (f == 0) wacc[wave] = local;
    __syncthreads();
    if (threadIdx.x == 0)
        slots[n] = wacc[0] + wacc[1] + wacc[2] + wacc[3];
}

__global__ __launch_bounds__(256) void finalize_kernel(
        const double* __restrict__ ws,
        const float* __restrict__ mu_A, const float* __restrict__ lv_A,
        float* __restrict__ out) {
    const int lane = threadIdx.x & 63;
    const int wave = threadIdx.x >> 6;

    double a = 0.0, ki = 0.0;
    const double2* w2 = reinterpret_cast<const double2*>(ws);
    for (int i = threadIdx.x; i < AB2 / 2; i += 256) { double2 v = w2[i]; a += v.x + v.y; }
    for (int i = threadIdx.x; i < KB / 2; i += 256) { double2 v = w2[AB2 / 2 + i]; ki += v.x + v.y; }
#pragma unroll
    for (int m = 1; m < 64; m <<= 1) {
        a  += __shfl_xor(a, m, 64);
        ki += __shfl_xor(ki, m, 64);
    }

    // KL_A vs standard normal: wave w handles b = 8w..8w+7
    double ka = 0.0;
#pragma unroll 1
    for (int bb = 0; bb < 8; ++bb) {
        const int b = wave * 8 + bb;
        float lv0 = lv_A[b * ZAc + lane], lv1 = lv_A[b * ZAc + 64 + lane];
        float m0  = mu_A[b * ZAc + lane], m1  = mu_A[b * ZAc + 64 + lane];
        float slv = lv0 + lv1;
        float sc  = __expf(lv0) + __expf(lv1) + m0 * m0 + m1 * m1;
#pragma unroll
        for (int m = 1; m < 64; m <<= 1) {
            slv += __shfl_xor(slv, m, 64);
            sc  += __shfl_xor(sc, m, 64);
        }
        if (lane == 0)
            ka += (double)(0.5f * __expf(slv) - 128.0f + sc);
    }

    __shared__ double sa[4], ski[4], ska[4];
    if (lane == 0) { sa[wave] = a; ski[wave] = ki; ska[wave] = ka; }
    __syncthreads();
    if (threadIdx.x == 0) {
        double A  = (sa[0] + sa[1] + sa[2] + sa[3]) / 32.0;
        double KI = (ski[0] + ski[1] + ski[2] + ski[3]) / 32.0;
        double KA = (ska[0] + ska[1] + ska[2] + ska[3]) / 32.0;
        out[0] = (float)A;
        out[1] = (float)KA;
        out[2] = (float)KI;
        out[3] = (float)(-(A + KA + KI));
    }
}

extern "C" void kernel_launch(void* const* d_in, const int* in_sizes, int n_in,
                              void* d_out, int out_size, void* d_ws, size_t ws_size,
                              hipStream_t stream) {
    const float* Ah   = (const float*)d_in[0];   // A_hat_batch  [32,1024,1024]
    const float* At   = (const float*)d_in[1];   // A_true       [32,1024,1024]
    const float* mu_A = (const float*)d_in[4];   // [32,128]
    const float* lv_A = (const float*)d_in[5];   // [32,128]
    const float* mu_i = (const float*)d_in[6];   // [32,1024,64]
    const float* lv_i = (const float*)d_in[7];   // [32,1024,64]
    const float* z_a  = (const float*)d_in[8];   // [32,128]
    const float* Bmu  = (const float*)d_in[9];   // [1024,64,128]
    const float* Blv  = (const float*)d_in[10];  // [1024,64,128]

    double* ws = (double*)d_ws;   // 3072 doubles = 24 KB, all written every call
    float* out = (float*)d_out;

    hipLaunchKernelGGL(arecon_kernel, dim3(AB2), dim3(256), 0, stream,
                       (const float4*)Ah, (const float4*)At, ws);
    hipLaunchKernelGGL(kli_kernel, dim3(KB), dim3(256), 0, stream,
                       mu_i, lv_i, z_a, Bmu, Blv, ws + AB2);
    hipLaunchKernelGGL(finalize_kernel, dim3(1), dim3(256), 0, stream,
                       ws, mu_A, lv_A, out);
}

// Round 7
// 359.745 us; speedup vs baseline: 1.0428x; 1.0428x over previous
//
#include <hip/hip_runtime.h>

// ---------------------------------------------------------------------------
// GraphVAELoss, R7. Change vs R5: merge arecon + kli into ONE kernel
// (block-role split) so kli's VALU work executes inside arecon's memory
// stalls instead of serially after them.
// Evidence: three distinct arecon structures (R3/R5/R6) all pin at ~100us,
// 2.7 TB/s consumed, occupancy-insensitive (33%..70% same perf) -> memory
// system at ceiling for this window; the win left on the table is the
// serial kli dispatch. R2's merge failure was launch_bounds(256,4) spill
// (195MB scratch) + 17KB LDS on all blocks — both absent here (no cap,
// 64B LDS, kli path needs ~96 VGPR, no spill).
// ws layout (doubles): [0,4096) arecon partials, [4096,5120) kli partials.
// ---------------------------------------------------------------------------

static constexpr int BB  = 32;
static constexpr int NN  = 1024;
static constexpr int ZIc = 64;
static constexpr int ZAc = 128;
static constexpr int AB  = 4096;                  // arecon role blocks
static constexpr int KB  = 1024;                  // kli role blocks

#define EPSV 1e-10f
#define SPW  0.7f

// A_true is exactly {0,1}: t==1 -> log(a); t==0 -> 0.7*log(1-a).
// Bit-identical to t*log(a)+(1-t)*log(1-a) + sparsity scale on t==0.
__device__ __forceinline__ float ll_elem(float a, float t) {
    a = (a == 0.0f) ? EPSV : ((a == 1.0f) ? (1.0f - EPSV) : a);
    float x = (t == 0.0f) ? (1.0f - a) : a;
    float s = (t == 0.0f) ? SPW : 1.0f;
    return s * __logf(x);
}

__device__ __forceinline__ float ll4(float4 a, float4 t) {
    return ll_elem(a.x, t.x) + ll_elem(a.y, t.y) +
           ll_elem(a.z, t.z) + ll_elem(a.w, t.w);
}

__global__ __launch_bounds__(256) void merged_kernel(
        const float4* __restrict__ Ah, const float4* __restrict__ At,
        const float* __restrict__ mu_i, const float* __restrict__ lv_i,
        const float* __restrict__ z_a,
        const float* __restrict__ Bmu, const float* __restrict__ Blv,
        double* __restrict__ slots) {
    const int tid  = threadIdx.x;
    const int lane = tid & 63;

    __shared__ float  wsum[4];    // arecon path
    __shared__ double wacc[4];    // kli path

    if (blockIdx.x >= KB) {
        // ---------------- arecon role: blocks [KB, KB+AB) ----------------
        const int ab = blockIdx.x - KB;
        const size_t base = (size_t)ab * 2048 + tid;

        float4 a0 = Ah[base +    0];  float4 t0 = At[base +    0];
        float4 a1 = Ah[base +  256];  float4 t1 = At[base +  256];
        float4 a2 = Ah[base +  512];  float4 t2 = At[base +  512];
        float4 a3 = Ah[base +  768];  float4 t3 = At[base +  768];
        float4 a4 = Ah[base + 1024];  float4 t4 = At[base + 1024];
        float4 a5 = Ah[base + 1280];  float4 t5 = At[base + 1280];
        float4 a6 = Ah[base + 1536];  float4 t6 = At[base + 1536];
        float4 a7 = Ah[base + 1792];  float4 t7 = At[base + 1792];
        __builtin_amdgcn_sched_barrier(0);

        float lsum = 0.0f;
        lsum += ll4(a0, t0);
        lsum += ll4(a1, t1);
        lsum += ll4(a2, t2);
        lsum += ll4(a3, t3);
        lsum += ll4(a4, t4);
        lsum += ll4(a5, t5);
        lsum += ll4(a6, t6);
        lsum += ll4(a7, t7);

#pragma unroll
        for (int m = 1; m < 64; m <<= 1) lsum += __shfl_xor(lsum, m, 64);
        const int wv = tid >> 6;
        if (lane == 0) wsum[wv] = lsum;
        __syncthreads();
        if (tid == 0)
            slots[ab] = (double)(wsum[0] + wsum[1] + wsum[2] + wsum[3]);
    } else {
        // ---------------- kli role: blocks [0, KB), one per node ----------
        const int n    = blockIdx.x;
        const int wave = __builtin_amdgcn_readfirstlane(tid >> 6);
        const int f    = lane;

        const float4* bmu = reinterpret_cast<const float4*>(Bmu + ((size_t)n * ZIc + f) * ZAc);
        const float4* blv = reinterpret_cast<const float4*>(Blv + ((size_t)n * ZIc + f) * ZAc);

        float pm[8], pl[8];
#pragma unroll
        for (int i = 0; i < 8; ++i) { pm[i] = 0.0f; pl[i] = 0.0f; }

        float4 mA[4], lA[4], mB[4], lB[4];
#pragma unroll
        for (int q = 0; q < 4; ++q) { mA[q] = bmu[q]; lA[q] = blv[q]; }

#define KLI_COMPUTE(MV, LV, CC)                                               \
        {                                                                     \
            _Pragma("unroll")                                                 \
            for (int bi = 0; bi < 8; ++bi) {                                  \
                const int b = wave * 8 + bi;                                  \
                const float* zp = z_a + b * ZAc + (CC) * 16;                  \
                _Pragma("unroll")                                             \
                for (int q = 0; q < 4; ++q) {                                 \
                    float4 zz = *reinterpret_cast<const float4*>(zp + 4 * q); \
                    pm[bi] += MV[q].x * zz.x + MV[q].y * zz.y +               \
                              MV[q].z * zz.z + MV[q].w * zz.w;                \
                    pl[bi] += LV[q].x * zz.x + LV[q].y * zz.y +               \
                              LV[q].z * zz.z + LV[q].w * zz.w;                \
                }                                                             \
            }                                                                 \
        }

#pragma unroll 1
        for (int c = 0; c < 8; c += 2) {
#pragma unroll
            for (int q = 0; q < 4; ++q) { mB[q] = bmu[(c + 1) * 4 + q]; lB[q] = blv[(c + 1) * 4 + q]; }
            KLI_COMPUTE(mA, lA, c)
            if (c + 2 < 8) {
#pragma unroll
                for (int q = 0; q < 4; ++q) { mA[q] = bmu[(c + 2) * 4 + q]; lA[q] = blv[(c + 2) * 4 + q]; }
            }
            KLI_COMPUTE(mB, lB, c + 1)
        }
#undef KLI_COMPUTE

        double local = 0.0;
#pragma unroll
        for (int bi = 0; bi < 8; ++bi) {
            const int b = wave * 8 + bi;
            const size_t base = ((size_t)b * NN + n) * ZIc + f;
            float m1  = mu_i[base];
            float lv1 = lv_i[base];
            float d   = lv1 - pl[bi];                   // log-det ratio element
            float dm  = pm[bi] - m1;
            float sc  = __expf(d) + dm * dm * __expf(-pl[bi]);   // trace + inner
            float sd  = d;
#pragma unroll
            for (int m = 1; m < 64; m <<= 1) {
                sd += __shfl_xor(sd, m, 64);
                sc += __shfl_xor(sc, m, 64);
            }
            if (f == 0)
                local += (double)(0.5f * __expf(sd) - 64.0f + sc);
        }
        if (f == 0) wacc[wave] = local;
        __syncthreads();
        if (tid == 0)
            slots[AB + n] = wacc[0] + wacc[1] + wacc[2] + wacc[3];
    }
}

__global__ __launch_bounds__(256) void finalize_kernel(
        const double* __restrict__ ws,
        const float* __restrict__ mu_A, const float* __restrict__ lv_A,
        float* __restrict__ out) {
    const int lane = threadIdx.x & 63;
    const int wave = threadIdx.x >> 6;

    double a = 0.0, ki = 0.0;
    const double2* w2 = reinterpret_cast<const double2*>(ws);
    for (int i = threadIdx.x; i < AB / 2; i += 256) { double2 v = w2[i]; a += v.x + v.y; }
    for (int i = threadIdx.x; i < KB / 2; i += 256) { double2 v = w2[AB / 2 + i]; ki += v.x + v.y; }
#pragma unroll
    for (int m = 1; m < 64; m <<= 1) {
        a  += __shfl_xor(a, m, 64);
        ki += __shfl_xor(ki, m, 64);
    }

    // KL_A vs standard normal: wave w handles b = 8w..8w+7
    double ka = 0.0;
#pragma unroll 1
    for (int bb = 0; bb < 8; ++bb) {
        const int b = wave * 8 + bb;
        float lv0 = lv_A[b * ZAc + lane], lv1 = lv_A[b * ZAc + 64 + lane];
        float m0  = mu_A[b * ZAc + lane], m1  = mu_A[b * ZAc + 64 + lane];
        float slv = lv0 + lv1;
        float sc  = __expf(lv0) + __expf(lv1) + m0 * m0 + m1 * m1;
#pragma unroll
        for (int m = 1; m < 64; m <<= 1) {
            slv += __shfl_xor(slv, m, 64);
            sc  += __shfl_xor(sc, m, 64);
        }
        if (lane == 0)
            ka += (double)(0.5f * __expf(slv) - 128.0f + sc);
    }

    __shared__ double sa[4], ski[4], ska[4];
    if (lane == 0) { sa[wave] = a; ski[wave] = ki; ska[wave] = ka; }
    __syncthreads();
    if (threadIdx.x == 0) {
        double A  = (sa[0] + sa[1] + sa[2] + sa[3]) / 32.0;
        double KI = (ski[0] + ski[1] + ski[2] + ski[3]) / 32.0;
        double KA = (ska[0] + ska[1] + ska[2] + ska[3]) / 32.0;
        out[0] = (float)A;
        out[1] = (float)KA;
        out[2] = (float)KI;
        out[3] = (float)(-(A + KA + KI));
    }
}

extern "C" void kernel_launch(void* const* d_in, const int* in_sizes, int n_in,
                              void* d_out, int out_size, void* d_ws, size_t ws_size,
                              hipStream_t stream) {
    const float* Ah   = (const float*)d_in[0];   // A_hat_batch  [32,1024,1024]
    const float* At   = (const float*)d_in[1];   // A_true       [32,1024,1024]
    const float* mu_A = (const float*)d_in[4];   // [32,128]
    const float* lv_A = (const float*)d_in[5];   // [32,128]
    const float* mu_i = (const float*)d_in[6];   // [32,1024,64]
    const float* lv_i = (const float*)d_in[7];   // [32,1024,64]
    const float* z_a  = (const float*)d_in[8];   // [32,128]
    const float* Bmu  = (const float*)d_in[9];   // [1024,64,128]
    const float* Blv  = (const float*)d_in[10];  // [1024,64,128]

    double* ws = (double*)d_ws;   // 5120 doubles = 40 KB, all written every call
    float* out = (float*)d_out;

    hipLaunchKernelGGL(merged_kernel, dim3(KB + AB), dim3(256), 0, stream,
                       (const float4*)Ah, (const float4*)At,
                       mu_i, lv_i, z_a, Bmu, Blv, ws);
    hipLaunchKernelGGL(finalize_kernel, dim3(1), dim3(256), 0, stream,
                       ws, mu_A, lv_A, out);
}

// Round 9
// 352.425 us; speedup vs baseline: 1.0645x; 1.0208x over previous
//
#include <hip/hip_runtime.h>

// ---------------------------------------------------------------------------
// GraphVAELoss, R9 (= R8 resubmitted; R8 bench never acquired a GPU).
// Changes vs R7 (both small):
//  (1) role interleave: kli role on blockIdx%5==0 (exactly 1024 of 5120),
//      arecon on the rest — every scheduling generation mixes VALU-heavy kli
//      with memory-heavy arecon (R7 put kli first -> phases never co-resided).
//  (2) non-temporal (nt) loads for the 268MB A-stream (zero reuse).
// ws layout (doubles): [0,4096) arecon partials, [4096,5120) kli partials.
// ---------------------------------------------------------------------------

static constexpr int BB  = 32;
static constexpr int NN  = 1024;
static constexpr int ZIc = 64;
static constexpr int ZAc = 128;
static constexpr int AB  = 4096;                  // arecon role blocks
static constexpr int KB  = 1024;                  // kli role blocks

#define EPSV 1e-10f
#define SPW  0.7f

typedef __attribute__((ext_vector_type(4))) float f32x4;

// A_true is exactly {0,1}: t==1 -> log(a); t==0 -> 0.7*log(1-a).
// Bit-identical to t*log(a)+(1-t)*log(1-a) + sparsity scale on t==0.
__device__ __forceinline__ float ll_elem(float a, float t) {
    a = (a == 0.0f) ? EPSV : ((a == 1.0f) ? (1.0f - EPSV) : a);
    float x = (t == 0.0f) ? (1.0f - a) : a;
    float s = (t == 0.0f) ? SPW : 1.0f;
    return s * __logf(x);
}

__device__ __forceinline__ float ll4(f32x4 a, f32x4 t) {
    return ll_elem(a[0], t[0]) + ll_elem(a[1], t[1]) +
           ll_elem(a[2], t[2]) + ll_elem(a[3], t[3]);
}

__device__ __forceinline__ f32x4 ldnt(const f32x4* p) {
    return __builtin_nontemporal_load(p);
}

__global__ __launch_bounds__(256) void merged_kernel(
        const f32x4* __restrict__ Ah, const f32x4* __restrict__ At,
        const float* __restrict__ mu_i, const float* __restrict__ lv_i,
        const float* __restrict__ z_a,
        const float* __restrict__ Bmu, const float* __restrict__ Blv,
        double* __restrict__ slots) {
    const int tid  = threadIdx.x;
    const int lane = tid & 63;

    __shared__ float  wsum[4];    // arecon path
    __shared__ double wacc[4];    // kli path

    const int bid = blockIdx.x;
    const int kn  = bid / 5;                     // kli node id if role==kli

    if (bid % 5 != 0) {
        // ---------------- arecon role (4 of every 5 blocks) ---------------
        const int ab = bid - kn - 1;             // 0..4095 bijective
        const size_t base = (size_t)ab * 2048 + tid;

        f32x4 a0 = ldnt(Ah + base +    0);  f32x4 t0 = ldnt(At + base +    0);
        f32x4 a1 = ldnt(Ah + base +  256);  f32x4 t1 = ldnt(At + base +  256);
        f32x4 a2 = ldnt(Ah + base +  512);  f32x4 t2 = ldnt(At + base +  512);
        f32x4 a3 = ldnt(Ah + base +  768);  f32x4 t3 = ldnt(At + base +  768);
        f32x4 a4 = ldnt(Ah + base + 1024);  f32x4 t4 = ldnt(At + base + 1024);
        f32x4 a5 = ldnt(Ah + base + 1280);  f32x4 t5 = ldnt(At + base + 1280);
        f32x4 a6 = ldnt(Ah + base + 1536);  f32x4 t6 = ldnt(At + base + 1536);
        f32x4 a7 = ldnt(Ah + base + 1792);  f32x4 t7 = ldnt(At + base + 1792);
        __builtin_amdgcn_sched_barrier(0);

        float lsum = 0.0f;
        lsum += ll4(a0, t0);
        lsum += ll4(a1, t1);
        lsum += ll4(a2, t2);
        lsum += ll4(a3, t3);
        lsum += ll4(a4, t4);
        lsum += ll4(a5, t5);
        lsum += ll4(a6, t6);
        lsum += ll4(a7, t7);

#pragma unroll
        for (int m = 1; m < 64; m <<= 1) lsum += __shfl_xor(lsum, m, 64);
        const int wv = tid >> 6;
        if (lane == 0) wsum[wv] = lsum;
        __syncthreads();
        if (tid == 0)
            slots[ab] = (double)(wsum[0] + wsum[1] + wsum[2] + wsum[3]);
    } else {
        // ---------------- kli role (every 5th block), node kn -------------
        const int n    = kn;
        const int wave = __builtin_amdgcn_readfirstlane(tid >> 6);
        const int f    = lane;

        const float4* bmu = reinterpret_cast<const float4*>(Bmu + ((size_t)n * ZIc + f) * ZAc);
        const float4* blv = reinterpret_cast<const float4*>(Blv + ((size_t)n * ZIc + f) * ZAc);

        float pm[8], pl[8];
#pragma unroll
        for (int i = 0; i < 8; ++i) { pm[i] = 0.0f; pl[i] = 0.0f; }

        float4 mA[4], lA[4], mB[4], lB[4];
#pragma unroll
        for (int q = 0; q < 4; ++q) { mA[q] = bmu[q]; lA[q] = blv[q]; }

#define KLI_COMPUTE(MV, LV, CC)                                               \
        {                                                                     \
            _Pragma("unroll")                                                 \
            for (int bi = 0; bi < 8; ++bi) {                                  \
                const int b = wave * 8 + bi;                                  \
                const float* zp = z_a + b * ZAc + (CC) * 16;                  \
                _Pragma("unroll")                                             \
                for (int q = 0; q < 4; ++q) {                                 \
                    float4 zz = *reinterpret_cast<const float4*>(zp + 4 * q); \
                    pm[bi] += MV[q].x * zz.x + MV[q].y * zz.y +               \
                              MV[q].z * zz.z + MV[q].w * zz.w;                \
                    pl[bi] += LV[q].x * zz.x + LV[q].y * zz.y +               \
                              LV[q].z * zz.z + LV[q].w * zz.w;                \
                }                                                             \
            }                                                                 \
        }

#pragma unroll 1
        for (int c = 0; c < 8; c += 2) {
#pragma unroll
            for (int q = 0; q < 4; ++q) { mB[q] = bmu[(c + 1) * 4 + q]; lB[q] = blv[(c + 1) * 4 + q]; }
            KLI_COMPUTE(mA, lA, c)
            if (c + 2 < 8) {
#pragma unroll
                for (int q = 0; q < 4; ++q) { mA[q] = bmu[(c + 2) * 4 + q]; lA[q] = blv[(c + 2) * 4 + q]; }
            }
            KLI_COMPUTE(mB, lB, c + 1)
        }
#undef KLI_COMPUTE

        double local = 0.0;
#pragma unroll
        for (int bi = 0; bi < 8; ++bi) {
            const int b = wave * 8 + bi;
            const size_t base = ((size_t)b * NN + n) * ZIc + f;
            float m1  = mu_i[base];
            float lv1 = lv_i[base];
            float d   = lv1 - pl[bi];                   // log-det ratio element
            float dm  = pm[bi] - m1;
            float sc  = __expf(d) + dm * dm * __expf(-pl[bi]);   // trace + inner
            float sd  = d;
#pragma unroll
            for (int m = 1; m < 64; m <<= 1) {
                sd += __shfl_xor(sd, m, 64);
                sc += __shfl_xor(sc, m, 64);
            }
            if (f == 0)
                local += (double)(0.5f * __expf(sd) - 64.0f + sc);
        }
        if (f == 0) wacc[wave] = local;
        __syncthreads();
        if (tid == 0)
            slots[AB + n] = wacc[0] + wacc[1] + wacc[2] + wacc[3];
    }
}

__global__ __launch_bounds__(256) void finalize_kernel(
        const double* __restrict__ ws,
        const float* __restrict__ mu_A, const float* __restrict__ lv_A,
        float* __restrict__ out) {
    const int lane = threadIdx.x & 63;
    const int wave = threadIdx.x >> 6;

    double a = 0.0, ki = 0.0;
    const double2* w2 = reinterpret_cast<const double2*>(ws);
    for (int i = threadIdx.x; i < AB / 2; i += 256) { double2 v = w2[i]; a += v.x + v.y; }
    for (int i = threadIdx.x; i < KB / 2; i += 256) { double2 v = w2[AB / 2 + i]; ki += v.x + v.y; }
#pragma unroll
    for (int m = 1; m < 64; m <<= 1) {
        a  += __shfl_xor(a, m, 64);
        ki += __shfl_xor(ki, m, 64);
    }

    // KL_A vs standard normal: wave w handles b = 8w..8w+7
    double ka = 0.0;
#pragma unroll 1
    for (int bb = 0; bb < 8; ++bb) {
        const int b = wave * 8 + bb;
        float lv0 = lv_A[b * ZAc + lane], lv1 = lv_A[b * ZAc + 64 + lane];
        float m0  = mu_A[b * ZAc + lane], m1  = mu_A[b * ZAc + 64 + lane];
        float slv = lv0 + lv1;
        float sc  = __expf(lv0) + __expf(lv1) + m0 * m0 + m1 * m1;
#pragma unroll
        for (int m = 1; m < 64; m <<= 1) {
            slv += __shfl_xor(slv, m, 64);
            sc  += __shfl_xor(sc, m, 64);
        }
        if (lane == 0)
            ka += (double)(0.5f * __expf(slv) - 128.0f + sc);
    }

    __shared__ double sa[4], ski[4], ska[4];
    if (lane == 0) { sa[wave] = a; ski[wave] = ki; ska[wave] = ka; }
    __syncthreads();
    if (threadIdx.x == 0) {
        double A  = (sa[0] + sa[1] + sa[2] + sa[3]) / 32.0;
        double KI = (ski[0] + ski[1] + ski[2] + ski[3]) / 32.0;
        double KA = (ska[0] + ska[1] + ska[2] + ska[3]) / 32.0;
        out[0] = (float)A;
        out[1] = (float)KA;
        out[2] = (float)KI;
        out[3] = (float)(-(A + KA + KI));
    }
}

extern "C" void kernel_launch(void* const* d_in, const int* in_sizes, int n_in,
                              void* d_out, int out_size, void* d_ws, size_t ws_size,
                              hipStream_t stream) {
    const float* Ah   = (const float*)d_in[0];   // A_hat_batch  [32,1024,1024]
    const float* At   = (const float*)d_in[1];   // A_true       [32,1024,1024]
    const float* mu_A = (const float*)d_in[4];   // [32,128]
    const float* lv_A = (const float*)d_in[5];   // [32,128]
    const float* mu_i = (const float*)d_in[6];   // [32,1024,64]
    const float* lv_i = (const float*)d_in[7];   // [32,1024,64]
    const float* z_a  = (const float*)d_in[8];   // [32,128]
    const float* Bmu  = (const float*)d_in[9];   // [1024,64,128]
    const float* Blv  = (const float*)d_in[10];  // [1024,64,128]

    double* ws = (double*)d_ws;   // 5120 doubles = 40 KB, all written every call
    float* out = (float*)d_out;

    hipLaunchKernelGGL(merged_kernel, dim3(KB + AB), dim3(256), 0, stream,
                       (const f32x4*)Ah, (const f32x4*)At,
                       mu_i, lv_i, z_a, Bmu, Blv, ws);
    hipLaunchKernelGGL(finalize_kernel, dim3(1), dim3(256), 0, stream,
                       ws, mu_A, lv_A, out);
}